// Round 5
// baseline (35.298 us; speedup 1.0000x reference)
//
#include <hip/hip_runtime.h>

// query:          [N=8, C=640, H=48, W=48] f32
// dynamic_filter: [N=8, 2304, 9, 1] f32   (per-pixel 3x3 taps, shared over C)
// out1 = relu(dynamic 3x3 conv): [8,640,48,48] f32
// out2 = zeros_like(dynamic_filter)
//
// R5 structure: 1 thread = 1 aligned float4 strip x CH=4 channels.
// ALL loads (9 tap-f4 + 4ch x 9 q-values) are issued before a single
// asm-join that forces them register-resident -> one overlapped memory
// latency per wave instead of ~45 serial ones (R4 showed VGPR=40: the
// compiler had sunk/spilled everything and serialized the loads).
#define N_   8
#define C_   640
#define H_   48
#define W_   48
#define K_   9
#define CH   4
#define NCC  (C_ / CH)          // 160 channel chunks
#define BLK  256
#define OUT1_ELEMS ((size_t)N_ * C_ * H_ * W_)   // 11,796,480
#define OUT2_ELEMS ((size_t)N_ * H_ * W_ * K_)   //    165,888

typedef float f4 __attribute__((ext_vector_type(4)));

__global__ __launch_bounds__(BLK, 3) void dynconv(
    const float* __restrict__ q,
    const float* __restrict__ df,
    float* __restrict__ out)
{
    const int g  = blockIdx.x * BLK + threadIdx.x;   // 2880*256 = 8*160*576 exact
    const int w4 = g % 12;
    const int h  = (g / 12) % H_;
    const int cc = (g / (12 * H_)) % NCC;
    const int n  = g / (12 * H_ * NCC);
    const int w0 = w4 * 4;
    const int c0 = cc * CH;

    // ---- zero out2 (folded in; no separate memset dispatch) ----
    if (g < (int)OUT2_ELEMS) out[OUT1_ELEMS + g] = 0.f;

    // ---- clamped, always-valid offsets (relative to strip base) ----
    int roff[3], loff[3], goff[3];
#pragma unroll
    for (int dy = 0; dy < 3; ++dy) {
        int r  = h + dy - 1;
        int rc = min(max(r, 0), H_ - 1);
        roff[dy] = (rc - h) * W_;
        loff[dy] = roff[dy] + ((w4 > 0)  ? -1 : 0);
        goff[dy] = roff[dy] + ((w4 < 11) ?  4 : 3);
    }

    const size_t plane = (size_t)H_ * W_;
    const float* qbase = q   + ((size_t)(n * C_ + c0)) * plane + h * W_ + w0;
    float*       obase = out + ((size_t)(n * C_ + c0)) * plane + h * W_ + w0;

    // ---- issue ALL loads: 9 tap-f4 + CH x (3 f4 + 6 scalars) ----
    const f4* dfp = (const f4*)(df + (size_t)(n * (H_ * W_) + h * W_ + w0) * K_);
    f4 t0 = dfp[0], t1 = dfp[1], t2 = dfp[2], t3 = dfp[3], t4 = dfp[4],
       t5 = dfp[5], t6 = dfp[6], t7 = dfp[7], t8 = dfp[8];

    f4 mm[CH][3]; float ll[CH][3], rr[CH][3];
#pragma unroll
    for (int ci = 0; ci < CH; ++ci) {
        const float* qp = qbase + (size_t)ci * plane;
#pragma unroll
        for (int dy = 0; dy < 3; ++dy) {
            mm[ci][dy] = *(const f4*)(qp + roff[dy]);
            ll[ci][dy] = qp[loff[dy]];
            rr[ci][dy] = qp[goff[dy]];
        }
    }

    // ---- join: force everything register-resident HERE (one overlapped wait)
    asm volatile("" : "+v"(t0), "+v"(t1), "+v"(t2), "+v"(t3), "+v"(t4),
                      "+v"(t5), "+v"(t6), "+v"(t7), "+v"(t8));
    asm volatile("" : "+v"(mm[0][0]), "+v"(mm[0][1]), "+v"(mm[0][2]),
                      "+v"(mm[1][0]), "+v"(mm[1][1]), "+v"(mm[1][2]),
                      "+v"(mm[2][0]), "+v"(mm[2][1]), "+v"(mm[2][2]),
                      "+v"(mm[3][0]), "+v"(mm[3][1]), "+v"(mm[3][2]));
    asm volatile("" : "+v"(ll[0][0]), "+v"(ll[0][1]), "+v"(ll[0][2]),
                      "+v"(ll[1][0]), "+v"(ll[1][1]), "+v"(ll[1][2]),
                      "+v"(ll[2][0]), "+v"(ll[2][1]), "+v"(ll[2][2]),
                      "+v"(ll[3][0]), "+v"(ll[3][1]), "+v"(ll[3][2]),
                      "+v"(rr[0][0]), "+v"(rr[0][1]), "+v"(rr[0][2]),
                      "+v"(rr[1][0]), "+v"(rr[1][1]), "+v"(rr[1][2]),
                      "+v"(rr[2][0]), "+v"(rr[2][1]), "+v"(rr[2][2]),
                      "+v"(rr[3][0]), "+v"(rr[3][1]), "+v"(rr[3][2]));

    // ---- unpack taps; boundary-fold via unconditional multiplicative masks
    float f[36];
    f[ 0]=t0.x; f[ 1]=t0.y; f[ 2]=t0.z; f[ 3]=t0.w;
    f[ 4]=t1.x; f[ 5]=t1.y; f[ 6]=t1.z; f[ 7]=t1.w;
    f[ 8]=t2.x; f[ 9]=t2.y; f[10]=t2.z; f[11]=t2.w;
    f[12]=t3.x; f[13]=t3.y; f[14]=t3.z; f[15]=t3.w;
    f[16]=t4.x; f[17]=t4.y; f[18]=t4.z; f[19]=t4.w;
    f[20]=t5.x; f[21]=t5.y; f[22]=t5.z; f[23]=t5.w;
    f[24]=t6.x; f[25]=t6.y; f[26]=t6.z; f[27]=t6.w;
    f[28]=t7.x; f[29]=t7.y; f[30]=t7.z; f[31]=t7.w;
    f[32]=t8.x; f[33]=t8.y; f[34]=t8.z; f[35]=t8.w;

    const float tm = (h == 0)      ? 0.f : 1.f;
    const float bm = (h == H_ - 1) ? 0.f : 1.f;
    const float lm = (w4 == 0)     ? 0.f : 1.f;
    const float rm = (w4 == 11)    ? 0.f : 1.f;
#pragma unroll
    for (int p = 0; p < 4; ++p) {
        f[p*9+0] *= tm; f[p*9+1] *= tm; f[p*9+2] *= tm;
        f[p*9+6] *= bm; f[p*9+7] *= bm; f[p*9+8] *= bm;
    }
    f[ 0] *= lm; f[ 3] *= lm; f[ 6] *= lm;   // pixel0 left column
    f[29] *= rm; f[32] *= rm; f[35] *= rm;   // pixel3 right column

    // ---- compute + store: 36 FMAs per channel, all operands in VGPRs ----
#pragma unroll
    for (int ci = 0; ci < CH; ++ci) {
        f4 acc = (f4){0.f, 0.f, 0.f, 0.f};
#pragma unroll
        for (int dy = 0; dy < 3; ++dy) {
            const int fb = dy * 3;
            const f4 m = mm[ci][dy];
            acc.x = fmaf(f[ 0 + fb], ll[ci][dy], acc.x);
            acc.x = fmaf(f[ 1 + fb], m.x,        acc.x);
            acc.x = fmaf(f[ 2 + fb], m.y,        acc.x);

            acc.y = fmaf(f[ 9 + fb], m.x,        acc.y);
            acc.y = fmaf(f[10 + fb], m.y,        acc.y);
            acc.y = fmaf(f[11 + fb], m.z,        acc.y);

            acc.z = fmaf(f[18 + fb], m.y,        acc.z);
            acc.z = fmaf(f[19 + fb], m.z,        acc.z);
            acc.z = fmaf(f[20 + fb], m.w,        acc.z);

            acc.w = fmaf(f[27 + fb], m.z,        acc.w);
            acc.w = fmaf(f[28 + fb], m.w,        acc.w);
            acc.w = fmaf(f[29 + fb], rr[ci][dy], acc.w);
        }
        acc.x = fmaxf(acc.x, 0.f);
        acc.y = fmaxf(acc.y, 0.f);
        acc.z = fmaxf(acc.z, 0.f);
        acc.w = fmaxf(acc.w, 0.f);
        *(f4*)(obase + (size_t)ci * plane) = acc;
    }
}

extern "C" void kernel_launch(void* const* d_in, const int* in_sizes, int n_in,
                              void* d_out, int out_size, void* d_ws, size_t ws_size,
                              hipStream_t stream)
{
    const float* q  = (const float*)d_in[0];
    const float* df = (const float*)d_in[1];
    float* out = (float*)d_out;

    const int total_threads = N_ * NCC * H_ * 12;        // 737,280
    const int blocks = total_threads / BLK;              // 2880
    dynconv<<<blocks, BLK, 0, stream>>>(q, df, out);
}

// Round 6
// 30.553 us; speedup vs baseline: 1.1553x; 1.1553x over previous
//
#include <hip/hip_runtime.h>

// query:          [N=8, C=640, H=48, W=48] f32
// dynamic_filter: [N=8, 2304, 9, 1] f32   (per-pixel 3x3 taps, shared over C)
// out1 = relu(dynamic 3x3 conv): [8,640,48,48] f32
// out2 = zeros_like(dynamic_filter)
//
// R6 theory: perf across R2..R5 tracked channels-per-thread (tap-load
// amplification: df traffic = threads*144B = 42MB@CH10 .. 106MB@CH4, all
// L2/L3-side). Fix: CH=16 amortizes taps to 26MB total; depth-2 register
// prefetch + asm joins keep ~18 loads in flight; entire grid (2880 waves,
// 11.25/CU) co-resident via __launch_bounds__(256,3).
#define N_   8
#define C_   640
#define H_   48
#define W_   48
#define K_   9
#define CH   16
#define NCC  (C_ / CH)                      // 40 channel chunks
#define BLK  256
#define NTHREADS (N_ * NCC * H_ * 12)       // 184,320
#define NBLK (NTHREADS / BLK)               // 720 = 8 * 90 (XCD-bijective)
#define OUT1_ELEMS ((size_t)N_ * C_ * H_ * W_)   // 11,796,480
#define OUT2_ELEMS ((size_t)N_ * H_ * W_ * K_)   //    165,888

typedef float f4 __attribute__((ext_vector_type(4)));

#define JOIN_CH(m, l, r)                                              \
    asm volatile("" : "+v"(m[0]), "+v"(m[1]), "+v"(m[2]),             \
                      "+v"(l[0]), "+v"(l[1]), "+v"(l[2]),             \
                      "+v"(r[0]), "+v"(r[1]), "+v"(r[2]))

__global__ __launch_bounds__(BLK, 3) void dynconv(
    const float* __restrict__ q,
    const float* __restrict__ df,
    float* __restrict__ out)
{
    // XCD-aware swizzle: each XCD gets 90 consecutive blocks = one n slice
    const int bid = blockIdx.x;
    const int swz = (bid & 7) * (NBLK / 8) + (bid >> 3);
    const int g   = swz * BLK + threadIdx.x;

    const int w4 = g % 12;
    const int h  = (g / 12) % H_;
    const int cc = (g / (12 * H_)) % NCC;
    const int n  = g / (12 * H_ * NCC);
    const int w0 = w4 * 4;
    const int c0 = cc * CH;

    // ---- zero out2 (folded; swizzled g is a bijection on [0,NTHREADS)) ----
    if (g < (int)OUT2_ELEMS) out[OUT1_ELEMS + g] = 0.f;

    // ---- clamped, always-valid offsets (relative to strip base) ----
    int roff[3], loff[3], goff[3];
#pragma unroll
    for (int dy = 0; dy < 3; ++dy) {
        int r  = h + dy - 1;
        int rc = min(max(r, 0), H_ - 1);
        roff[dy] = (rc - h) * W_;
        loff[dy] = roff[dy] + ((w4 > 0)  ? -1 : 0);
        goff[dy] = roff[dy] + ((w4 < 11) ?  4 : 3);
    }

    const size_t plane = (size_t)H_ * W_;
    const float* qbase = q   + ((size_t)(n * C_ + c0)) * plane + h * W_ + w0;
    float*       obase = out + ((size_t)(n * C_ + c0)) * plane + h * W_ + w0;

    // ---- issue tap loads first (earliest complete) ----
    const f4* dfp = (const f4*)(df + (size_t)(n * (H_ * W_) + h * W_ + w0) * K_);
    f4 t0 = dfp[0], t1 = dfp[1], t2 = dfp[2], t3 = dfp[3], t4 = dfp[4],
       t5 = dfp[5], t6 = dfp[6], t7 = dfp[7], t8 = dfp[8];

    // ---- prologue: channels 0 and 1 in flight ----
    f4 m0[3], m1[3]; float l0[3], r0[3], l1[3], r1[3];
#pragma unroll
    for (int dy = 0; dy < 3; ++dy) {
        m0[dy] = *(const f4*)(qbase + roff[dy]);
        l0[dy] = qbase[loff[dy]];
        r0[dy] = qbase[goff[dy]];
    }
    {
        const float* qp = qbase + plane;
#pragma unroll
        for (int dy = 0; dy < 3; ++dy) {
            m1[dy] = *(const f4*)(qp + roff[dy]);
            l1[dy] = qp[loff[dy]];
            r1[dy] = qp[goff[dy]];
        }
    }

    // ---- unpack taps, fold boundaries via multiplicative masks ----
    float f[36];
    f[ 0]=t0.x; f[ 1]=t0.y; f[ 2]=t0.z; f[ 3]=t0.w;
    f[ 4]=t1.x; f[ 5]=t1.y; f[ 6]=t1.z; f[ 7]=t1.w;
    f[ 8]=t2.x; f[ 9]=t2.y; f[10]=t2.z; f[11]=t2.w;
    f[12]=t3.x; f[13]=t3.y; f[14]=t3.z; f[15]=t3.w;
    f[16]=t4.x; f[17]=t4.y; f[18]=t4.z; f[19]=t4.w;
    f[20]=t5.x; f[21]=t5.y; f[22]=t5.z; f[23]=t5.w;
    f[24]=t6.x; f[25]=t6.y; f[26]=t6.z; f[27]=t6.w;
    f[28]=t7.x; f[29]=t7.y; f[30]=t7.z; f[31]=t7.w;
    f[32]=t8.x; f[33]=t8.y; f[34]=t8.z; f[35]=t8.w;

    const float tm = (h == 0)      ? 0.f : 1.f;
    const float bm = (h == H_ - 1) ? 0.f : 1.f;
    const float lm = (w4 == 0)     ? 0.f : 1.f;
    const float rm = (w4 == 11)    ? 0.f : 1.f;
#pragma unroll
    for (int p = 0; p < 4; ++p) {
        f[p*9+0] *= tm; f[p*9+1] *= tm; f[p*9+2] *= tm;
        f[p*9+6] *= bm; f[p*9+7] *= bm; f[p*9+8] *= bm;
    }
    f[ 0] *= lm; f[ 3] *= lm; f[ 6] *= lm;   // pixel0 left column
    f[29] *= rm; f[32] *= rm; f[35] *= rm;   // pixel3 right column

    // ---- channel loop: consume ch ci, keep ch ci+1 in flight, issue ci+2 ----
#pragma unroll
    for (int ci = 0; ci < CH; ++ci) {
        JOIN_CH(m0, l0, r0);   // wait only on this channel's 9 loads

        f4 acc = (f4){0.f, 0.f, 0.f, 0.f};
#pragma unroll
        for (int dy = 0; dy < 3; ++dy) {
            const int fb = dy * 3;
            const f4 m = m0[dy];
            acc.x = fmaf(f[ 0 + fb], l0[dy], acc.x);
            acc.x = fmaf(f[ 1 + fb], m.x,    acc.x);
            acc.x = fmaf(f[ 2 + fb], m.y,    acc.x);

            acc.y = fmaf(f[ 9 + fb], m.x,    acc.y);
            acc.y = fmaf(f[10 + fb], m.y,    acc.y);
            acc.y = fmaf(f[11 + fb], m.z,    acc.y);

            acc.z = fmaf(f[18 + fb], m.y,    acc.z);
            acc.z = fmaf(f[19 + fb], m.z,    acc.z);
            acc.z = fmaf(f[20 + fb], m.w,    acc.z);

            acc.w = fmaf(f[27 + fb], m.z,    acc.w);
            acc.w = fmaf(f[28 + fb], m.w,    acc.w);
            acc.w = fmaf(f[29 + fb], r0[dy], acc.w);
        }
        acc.x = fmaxf(acc.x, 0.f);
        acc.y = fmaxf(acc.y, 0.f);
        acc.z = fmaxf(acc.z, 0.f);
        acc.w = fmaxf(acc.w, 0.f);
        *(f4*)(obase + (size_t)ci * plane) = acc;

        // rotate pipeline (SSA renaming after full unroll) + issue ci+2
        if (ci + 1 < CH) {
#pragma unroll
            for (int dy = 0; dy < 3; ++dy) {
                m0[dy] = m1[dy]; l0[dy] = l1[dy]; r0[dy] = r1[dy];
            }
            if (ci + 2 < CH) {
                const float* qp = qbase + (size_t)(ci + 2) * plane;
#pragma unroll
                for (int dy = 0; dy < 3; ++dy) {
                    m1[dy] = *(const f4*)(qp + roff[dy]);
                    l1[dy] = qp[loff[dy]];
                    r1[dy] = qp[goff[dy]];
                }
            }
        }
    }
}

extern "C" void kernel_launch(void* const* d_in, const int* in_sizes, int n_in,
                              void* d_out, int out_size, void* d_ws, size_t ws_size,
                              hipStream_t stream)
{
    const float* q  = (const float*)d_in[0];
    const float* df = (const float*)d_in[1];
    float* out = (float*)d_out;

    dynconv<<<NBLK, BLK, 0, stream>>>(q, df, out);
}

// Round 7
// 21.356 us; speedup vs baseline: 1.6528x; 1.4306x over previous
//
#include <hip/hip_runtime.h>

// query:          [N=8, C=640, H=48, W=48] f32
// dynamic_filter: [N=8, 2304, 9, 1] f32   (per-pixel 3x3 taps, shared over C)
// out1 = relu(dynamic 3x3 conv): [8,640,48,48] f32
// out2 = zeros_like(dynamic_filter)
//
// R7 theory: R2-R6 were TA/L1 request-rate bound: the 6 per-channel scalar
// edge loads are 16B-strided gathers costing ~64 TA-cy each (78k cy/CU total
// ~= the measured 30us). Fix: halos come from neighbor lanes via shuffles
// (LDS-permute pipe, not TA). Lane map = 16 lanes/row (12 active), so every
// wave-edge pull is an image boundary whose tap is already zero-masked.
#define N_   8
#define C_   640
#define H_   48
#define W_   48
#define K_   9
#define CH   16
#define NCC  (C_ / CH)              // 40
#define BLK  256                    // 16 rows x 16 lanes (12 active)
#define HB   3                      // 48 rows / 16 rows-per-block
#define NBLK (N_ * NCC * HB)        // 960 = 8 * 120 (XCD-bijective)
#define OUT1_ELEMS ((size_t)N_ * C_ * H_ * W_)   // 11,796,480
#define OUT2_ELEMS ((size_t)N_ * H_ * W_ * K_)   //    165,888

typedef float f4 __attribute__((ext_vector_type(4)));

__global__ __launch_bounds__(BLK, 4) void dynconv(
    const float* __restrict__ q,
    const float* __restrict__ df,
    float* __restrict__ out)
{
    const int tid = threadIdx.x;
    const int bid = blockIdx.x;
    // XCD swizzle: 120 consecutive work-ids per XCD = one full n (df L2-resident)
    const int swz = (bid & 7) * (NBLK / 8) + (bid >> 3);

    // ---- zero out2 (960*256 = 245,760 >= 165,888) ----
    {
        size_t g = (size_t)bid * BLK + tid;
        if (g < OUT2_ELEMS) out[OUT1_ELEMS + g] = 0.f;
    }

    const int p     = tid & 15;     // lane-in-row; active if p < 12
    const int rowid = tid >> 4;     // 0..15 rows per block
    if (p >= 12) return;            // idle lanes: tap-masked don't-care shuffle srcs

    const int hb = swz % HB;
    const int cc = (swz / HB) % NCC;
    const int n  = swz / (HB * NCC);
    const int h  = hb * 16 + rowid;
    const int w0 = p * 4;
    const int c0 = cc * CH;

    // ---- per-pixel taps: 36 contiguous floats, 144B-aligned -> 9 f4 loads ----
    const f4* dfp = (const f4*)(df + (size_t)(n * (H_ * W_) + h * W_ + w0) * K_);
    f4 t0 = dfp[0], t1 = dfp[1], t2 = dfp[2], t3 = dfp[3], t4 = dfp[4],
       t5 = dfp[5], t6 = dfp[6], t7 = dfp[7], t8 = dfp[8];

    // ---- row-clamped offsets (relative to strip base); taps absorb zeroing ----
    int roff[3];
#pragma unroll
    for (int dy = 0; dy < 3; ++dy) {
        int r  = h + dy - 1;
        int rc = min(max(r, 0), H_ - 1);
        roff[dy] = (rc - h) * W_;
    }

    const size_t plane = (size_t)H_ * W_;
    const float* qbase = q   + ((size_t)(n * C_ + c0)) * plane + h * W_ + w0;
    float*       obase = out + ((size_t)(n * C_ + c0)) * plane + h * W_ + w0;

    // ---- prologue: channels 0 and 1 in flight (3 f4 loads each, no gathers) ----
    f4 m0[3], m1[3];
#pragma unroll
    for (int dy = 0; dy < 3; ++dy) m0[dy] = *(const f4*)(qbase + roff[dy]);
    {
        const float* qp = qbase + plane;
#pragma unroll
        for (int dy = 0; dy < 3; ++dy) m1[dy] = *(const f4*)(qp + roff[dy]);
    }

    // ---- unpack taps; fold ALL boundary zeroing in via multiplicative masks ----
    float f[36];
    f[ 0]=t0.x; f[ 1]=t0.y; f[ 2]=t0.z; f[ 3]=t0.w;
    f[ 4]=t1.x; f[ 5]=t1.y; f[ 6]=t1.z; f[ 7]=t1.w;
    f[ 8]=t2.x; f[ 9]=t2.y; f[10]=t2.z; f[11]=t2.w;
    f[12]=t3.x; f[13]=t3.y; f[14]=t3.z; f[15]=t3.w;
    f[16]=t4.x; f[17]=t4.y; f[18]=t4.z; f[19]=t4.w;
    f[20]=t5.x; f[21]=t5.y; f[22]=t5.z; f[23]=t5.w;
    f[24]=t6.x; f[25]=t6.y; f[26]=t6.z; f[27]=t6.w;
    f[28]=t7.x; f[29]=t7.y; f[30]=t7.z; f[31]=t7.w;
    f[32]=t8.x; f[33]=t8.y; f[34]=t8.z; f[35]=t8.w;

    const float tm = (h == 0)      ? 0.f : 1.f;   // top row
    const float bm = (h == H_ - 1) ? 0.f : 1.f;   // bottom row
    const float lm = (p == 0)      ? 0.f : 1.f;   // image left  (w0==0)
    const float rm = (p == 11)     ? 0.f : 1.f;   // image right (w0==44)
#pragma unroll
    for (int px = 0; px < 4; ++px) {
        f[px*9+0] *= tm; f[px*9+1] *= tm; f[px*9+2] *= tm;
        f[px*9+6] *= bm; f[px*9+7] *= bm; f[px*9+8] *= bm;
    }
    f[ 0] *= lm; f[ 3] *= lm; f[ 6] *= lm;   // pixel0 left column
    f[29] *= rm; f[32] *= rm; f[35] *= rm;   // pixel3 right column

    // ---- channel loop: 3 f4 loads + 6 shuffles + 36 FMA + 1 f4 store ----
#pragma unroll
    for (int ci = 0; ci < CH; ++ci) {
        asm volatile("" : "+v"(m0[0]), "+v"(m0[1]), "+v"(m0[2]));

        float lft[3], rgt[3];
#pragma unroll
        for (int dy = 0; dy < 3; ++dy) {
            lft[dy] = __shfl_up(m0[dy].w, 1);    // neighbor strip's last px
            rgt[dy] = __shfl_down(m0[dy].x, 1);  // neighbor strip's first px
        }

        f4 acc = (f4){0.f, 0.f, 0.f, 0.f};
#pragma unroll
        for (int dy = 0; dy < 3; ++dy) {
            const int fb = dy * 3;
            const f4 m = m0[dy];
            acc.x = fmaf(f[ 0 + fb], lft[dy], acc.x);
            acc.x = fmaf(f[ 1 + fb], m.x,     acc.x);
            acc.x = fmaf(f[ 2 + fb], m.y,     acc.x);

            acc.y = fmaf(f[ 9 + fb], m.x,     acc.y);
            acc.y = fmaf(f[10 + fb], m.y,     acc.y);
            acc.y = fmaf(f[11 + fb], m.z,     acc.y);

            acc.z = fmaf(f[18 + fb], m.y,     acc.z);
            acc.z = fmaf(f[19 + fb], m.z,     acc.z);
            acc.z = fmaf(f[20 + fb], m.w,     acc.z);

            acc.w = fmaf(f[27 + fb], m.z,     acc.w);
            acc.w = fmaf(f[28 + fb], m.w,     acc.w);
            acc.w = fmaf(f[29 + fb], rgt[dy], acc.w);
        }
        acc.x = fmaxf(acc.x, 0.f);
        acc.y = fmaxf(acc.y, 0.f);
        acc.z = fmaxf(acc.z, 0.f);
        acc.w = fmaxf(acc.w, 0.f);
        *(f4*)(obase + (size_t)ci * plane) = acc;

        // rotate depth-2 pipeline + issue ci+2 (3 coalesced f4 loads)
        if (ci + 1 < CH) {
#pragma unroll
            for (int dy = 0; dy < 3; ++dy) m0[dy] = m1[dy];
            if (ci + 2 < CH) {
                const float* qp = qbase + (size_t)(ci + 2) * plane;
#pragma unroll
                for (int dy = 0; dy < 3; ++dy) m1[dy] = *(const f4*)(qp + roff[dy]);
            }
        }
    }
}

extern "C" void kernel_launch(void* const* d_in, const int* in_sizes, int n_in,
                              void* d_out, int out_size, void* d_ws, size_t ws_size,
                              hipStream_t stream)
{
    const float* q  = (const float*)d_in[0];
    const float* df = (const float*)d_in[1];
    float* out = (float*)d_out;

    dynconv<<<NBLK, BLK, 0, stream>>>(q, df, out);
}

// Round 8
// 20.500 us; speedup vs baseline: 1.7218x; 1.0418x over previous
//
#include <hip/hip_runtime.h>

// query:          [N=8, C=640, H=48, W=48] f32
// dynamic_filter: [N=8, 2304, 9, 1] f32   (per-pixel 3x3 taps, shared over C)
// out1 = relu(dynamic 3x3 conv): [8,640,48,48] f32
// out2 = zeros_like(dynamic_filter)
//
// R8: R7 removed the q-side strided gathers (30.5->21.4us). Remaining TA-line
// model: taps (9x f4 loads at 144B lane-stride = ~27 lines/instr) are ~36% of
// wave TA work. Fix: stage each block's contiguous 27.6KB df slice through LDS
// with block-coalesced loads (3 lines/instr), re-read per-thread via
// ds_read_b128. Plus depth-3 channel prefetch (9 q-loads in flight).
#define N_   8
#define C_   640
#define H_   48
#define W_   48
#define K_   9
#define CH   16
#define NCC  (C_ / CH)              // 40
#define BLK  256                    // 16 rows x 16 lanes (12 active)
#define HB   3                      // 48 rows / 16 rows-per-block
#define NBLK (N_ * NCC * HB)        // 960 = 8 * 120 (XCD-bijective)
#define DF_F4   1728                // 16 rows * 48 px * 9 taps / 4 = f4 count
#define OUT1_ELEMS ((size_t)N_ * C_ * H_ * W_)   // 11,796,480
#define OUT2_ELEMS ((size_t)N_ * H_ * W_ * K_)   //    165,888

typedef float f4 __attribute__((ext_vector_type(4)));

__global__ __launch_bounds__(BLK, 4) void dynconv(
    const float* __restrict__ q,
    const float* __restrict__ df,
    float* __restrict__ out)
{
    __shared__ f4 sdf[DF_F4];       // 27,648 B

    const int tid = threadIdx.x;
    const int bid = blockIdx.x;
    // XCD swizzle: 120 consecutive work-ids per XCD = one full n (df L2-resident)
    const int swz = (bid & 7) * (NBLK / 8) + (bid >> 3);

    // ---- zero out2 (960*256 = 245,760 >= 165,888) ----
    {
        size_t g = (size_t)bid * BLK + tid;
        if (g < OUT2_ELEMS) out[OUT1_ELEMS + g] = 0.f;
    }

    const int p     = tid & 15;     // lane-in-row; active if p < 12
    const int rowid = tid >> 4;     // 0..15 rows per block

    const int hb = swz % HB;
    const int cc = (swz / HB) % NCC;
    const int n  = swz / (HB * NCC);
    const int h  = hb * 16 + rowid;
    const int w0 = p * 4;
    const int c0 = cc * CH;

    // ---- stage df slice: issue block-coalesced global loads FIRST ----
    // slice = df[n][hb*16*48 .. +768)[9] : 27,648B contiguous, 16B-aligned
    const f4* dfg = (const f4*)(df + (size_t)n * (H_ * W_ * K_)
                                   + (size_t)hb * 16 * W_ * K_);
    f4 stg[7];
#pragma unroll
    for (int i = 0; i < 7; ++i) {
        int idx = tid + i * BLK;
        if (idx < DF_F4) stg[i] = dfg[idx];     // wave-uniform predicate
    }

    // ---- row-clamped offsets; taps absorb all boundary zeroing ----
    int roff[3];
#pragma unroll
    for (int dy = 0; dy < 3; ++dy) {
        int r  = h + dy - 1;
        int rc = min(max(r, 0), H_ - 1);
        roff[dy] = (rc - h) * W_;
    }

    const size_t plane = (size_t)H_ * W_;
    const float* qbase = q   + ((size_t)(n * C_ + c0)) * plane + h * W_ + w0;
    float*       obase = out + ((size_t)(n * C_ + c0)) * plane + h * W_ + w0;

    // ---- prologue: channels 0..2 in flight (only for active lanes) ----
    f4 m0[3], m1[3], m2[3];
    if (p < 12) {
#pragma unroll
        for (int dy = 0; dy < 3; ++dy) m0[dy] = *(const f4*)(qbase + roff[dy]);
        const float* qp1 = qbase + plane;
#pragma unroll
        for (int dy = 0; dy < 3; ++dy) m1[dy] = *(const f4*)(qp1 + roff[dy]);
        const float* qp2 = qbase + 2 * plane;
#pragma unroll
        for (int dy = 0; dy < 3; ++dy) m2[dy] = *(const f4*)(qp2 + roff[dy]);
    }

    // ---- LDS writes (each waits only its own staged load), then barrier ----
#pragma unroll
    for (int i = 0; i < 7; ++i) {
        int idx = tid + i * BLK;
        if (idx < DF_F4) sdf[idx] = stg[i];
    }
    __syncthreads();

    if (p >= 12) return;            // idle lanes done (past the barrier)

    // ---- taps from LDS: 9x ds_read_b128, per-thread layout ----
    float f[36];
    {
        const f4* tp = &sdf[rowid * 108 + p * 9];
#pragma unroll
        for (int i = 0; i < 9; ++i) {
            f4 v = tp[i];
            f[4*i+0] = v.x; f[4*i+1] = v.y; f[4*i+2] = v.z; f[4*i+3] = v.w;
        }
    }

    const float tm = (h == 0)      ? 0.f : 1.f;   // top row
    const float bm = (h == H_ - 1) ? 0.f : 1.f;   // bottom row
    const float lm = (p == 0)      ? 0.f : 1.f;   // image left  (w0==0)
    const float rm = (p == 11)     ? 0.f : 1.f;   // image right (w0==44)
#pragma unroll
    for (int px = 0; px < 4; ++px) {
        f[px*9+0] *= tm; f[px*9+1] *= tm; f[px*9+2] *= tm;
        f[px*9+6] *= bm; f[px*9+7] *= bm; f[px*9+8] *= bm;
    }
    f[ 0] *= lm; f[ 3] *= lm; f[ 6] *= lm;   // pixel0 left column
    f[29] *= rm; f[32] *= rm; f[35] *= rm;   // pixel3 right column

    // ---- channel loop: 3 f4 loads + 6 shuffles + 36 FMA + 1 f4 store ----
#pragma unroll
    for (int ci = 0; ci < CH; ++ci) {
        asm volatile("" : "+v"(m0[0]), "+v"(m0[1]), "+v"(m0[2]));

        float lft[3], rgt[3];
#pragma unroll
        for (int dy = 0; dy < 3; ++dy) {
            lft[dy] = __shfl_up(m0[dy].w, 1);    // neighbor strip's last px
            rgt[dy] = __shfl_down(m0[dy].x, 1);  // neighbor strip's first px
        }

        f4 acc = (f4){0.f, 0.f, 0.f, 0.f};
#pragma unroll
        for (int dy = 0; dy < 3; ++dy) {
            const int fb = dy * 3;
            const f4 m = m0[dy];
            acc.x = fmaf(f[ 0 + fb], lft[dy], acc.x);
            acc.x = fmaf(f[ 1 + fb], m.x,     acc.x);
            acc.x = fmaf(f[ 2 + fb], m.y,     acc.x);

            acc.y = fmaf(f[ 9 + fb], m.x,     acc.y);
            acc.y = fmaf(f[10 + fb], m.y,     acc.y);
            acc.y = fmaf(f[11 + fb], m.z,     acc.y);

            acc.z = fmaf(f[18 + fb], m.y,     acc.z);
            acc.z = fmaf(f[19 + fb], m.z,     acc.z);
            acc.z = fmaf(f[20 + fb], m.w,     acc.z);

            acc.w = fmaf(f[27 + fb], m.z,     acc.w);
            acc.w = fmaf(f[28 + fb], m.w,     acc.w);
            acc.w = fmaf(f[29 + fb], rgt[dy], acc.w);
        }
        acc.x = fmaxf(acc.x, 0.f);
        acc.y = fmaxf(acc.y, 0.f);
        acc.z = fmaxf(acc.z, 0.f);
        acc.w = fmaxf(acc.w, 0.f);
        *(f4*)(obase + (size_t)ci * plane) = acc;

        // rotate depth-3 pipeline + issue ci+3 (3 coalesced f4 loads)
        if (ci + 1 < CH) {
#pragma unroll
            for (int dy = 0; dy < 3; ++dy) { m0[dy] = m1[dy]; m1[dy] = m2[dy]; }
            if (ci + 3 < CH) {
                const float* qp = qbase + (size_t)(ci + 3) * plane;
#pragma unroll
                for (int dy = 0; dy < 3; ++dy) m2[dy] = *(const f4*)(qp + roff[dy]);
            }
        }
    }
}

extern "C" void kernel_launch(void* const* d_in, const int* in_sizes, int n_in,
                              void* d_out, int out_size, void* d_ws, size_t ws_size,
                              hipStream_t stream)
{
    const float* q  = (const float*)d_in[0];
    const float* df = (const float*)d_in[1];
    float* out = (float*)d_out;

    dynconv<<<NBLK, BLK, 0, stream>>>(q, df, out);
}